// Round 7
// baseline (126.240 us; speedup 1.0000x reference)
//
#include <hip/hip_runtime.h>

// LearnedTaskSpecificLinear: out[n,o] = sum_i x[n,i] * W[task_ids[n], i, o]
// x: [2048,512] f32, task_ids: [2048] i32, W: [64,512,512] f32, out: [2048,512] f32
//
// Round 11: 16-wave single-barrier block (max staging TLP, min lockstep).
//   R8 (lockstep, 2 w/SIMD) = 23.1us, R9 (prefetch, 2 w/SIMD) = 23.7us,
//   R10 (barrier-free, 1 w/SIMD) = 23.9us -> schedule shape is NOT the lever;
//   load-issue duty cycle is. Fill kernels hit 6.3 TB/s with many trivial
//   waves; we hit ~3 TB/s. Fix: 4 waves/SIMD all streaming W concurrently,
//   and only ONE barrier in the entire kernel.
//   grid 256 blocks x 1024 thr (16 waves), 1 block/CU. Block owns 4 units
//   (unit = task x 32-col chunk): task = (bid&7)|((bid>>5)<<3) (task's 4
//   blocks on one XCD -> x L2-resident), quad = (bid>>3)&3, chunks quad*4+u.
//   LDS: Wt[4][32x512] f16 (128 KB) + rl[4][256] (2 KB) = 130 KB.
//   Per wave (unit u = wv>>2, sub = wv&3): preload tids -> issue W stripe
//   2*sub -> ballot scan (covers load latency; 4 waves/unit write identical
//   list values - benign) -> stage stripe -> issue/stage stripe 2*sub+1 ->
//   __syncthreads (the only barrier) -> wave sub computes groups sub, sub+4...
//   of its unit (16 rows x 32 cols each, quarter-pipelined x gather, verified
//   R5/R10 XOR-swizzle po = oct ^ (c&7) and MFMA/store mappings).
//   Register audit (R6 lesson): staging tvv 32 + wr 32 + addr ~20 = ~85;
//   compute xqA/xqB 64 + paf 32 + acc 8 ~ 110 < 128 cap @ launch_bounds(1024,4).

#define NDIM 512
#define KDIM 512
#define NCOL 32
#define LISTCAP 256

typedef _Float16 f16x8 __attribute__((ext_vector_type(8)));
typedef float    f32x4 __attribute__((ext_vector_type(4)));
typedef int      i32x4 __attribute__((ext_vector_type(4)));

__global__ __launch_bounds__(1024, 4) void k_big(
    const float* __restrict__ x,
    const int*   __restrict__ tids,
    const float* __restrict__ W,
    float*       __restrict__ out,
    int n_rows)
{
    const int tid  = threadIdx.x;
    const int lane = tid & 63;
    const int wv   = tid >> 6;          // 0..15
    const int ml   = lane & 15;
    const int q    = lane >> 4;
    const int sc4  = (lane & 7) * 4;    // 4-col group within the 32-col chunk
    const int ol   = lane >> 3;         // lane's base k-octet 0..7

    const int u    = wv >> 2;           // unit 0..3 within block
    const int sub  = wv & 3;            // staging/compute sub-wave within unit

    const int bid   = blockIdx.x;
    const int task  = (bid & 7) | ((bid >> 5) << 3);
    const int chunk = ((bid >> 3) & 3) * 4 + u;
    const int c0    = chunk * NCOL;

    __shared__ __align__(16) _Float16 Wt[4][NCOL * KDIM];   // 128 KB
    __shared__ unsigned short rl[4][LISTCAP];               // 2 KB

    _Float16*       Wm  = &Wt[u][0];
    unsigned short* rlm = &rl[u][0];

    const float* Wg = W + (size_t)task * KDIM * NDIM + c0;

    // ---- preload all tids (8 x i32x4 per wave; each wave covers all 2048 rows)
    i32x4 tvv[8];
    #pragma unroll
    for (int cb = 0; cb < 8; ++cb) {
        const int r4 = cb * 256 + lane * 4;
        if (r4 + 3 < n_rows) {
            tvv[cb] = *(const i32x4*)(tids + r4);
        } else {
            #pragma unroll
            for (int j = 0; j < 4; ++j)
                tvv[cb][j] = (r4 + j < n_rows) ? tids[r4 + j] : -1;
        }
    }

    // ---- W staging: wave handles stripes 2*sub and 2*sub+1 of its unit.
    // Stripe s covers k-octets oct = ol + 8*s (8 octets), 8 rows each.
    float4 wr[8];
    auto issueS = [&](int s) {
        const size_t kb = (size_t)(ol + 8 * s) * 8;
        #pragma unroll
        for (int j = 0; j < 8; ++j)
            wr[j] = *(const float4*)(Wg + (kb + j) * NDIM + sc4);
    };
    auto stageS = [&](int s) {
        const int oct = ol + 8 * s;
        #pragma unroll
        for (int j2 = 0; j2 < 4; ++j2) {
            f16x8 h8;
            #pragma unroll
            for (int j = 0; j < 8; ++j)
                h8[j] = (_Float16)(((const float*)&wr[j])[j2]);
            const int c  = sc4 + j2;
            const int po = oct ^ (c & 7);
            *(f16x8*)&Wm[c * KDIM + po * 8] = h8;
        }
    };

    issueS(2 * sub);

    // ---- ballot scan (register-only; runs under the stripe's load latency).
    // All 4 waves of a unit write IDENTICAL values to rlm -> benign.
    int cnt = 0;
    #pragma unroll
    for (int cb = 0; cb < 8; ++cb) {
        #pragma unroll
        for (int j = 0; j < 4; ++j) {
            const bool m = (tvv[cb][j] == task);
            const unsigned long long bal = __ballot(m);
            const int rank = __popcll(bal & ((1ull << lane) - 1ull));
            const int slot = cnt + rank;
            if (m && slot < LISTCAP) rlm[slot] = (unsigned short)(cb * 256 + lane * 4 + j);
            cnt += __popcll(bal);
        }
    }
    if (cnt > LISTCAP) cnt = LISTCAP;

    stageS(2 * sub);
    issueS(2 * sub + 1);
    stageS(2 * sub + 1);

    __syncthreads();   // the ONLY barrier in the kernel

    // ---- compute: wave sub of unit u takes row groups sub, sub+4, ...
    f32x4 xqA[8], xqB[8];
    auto issueQ = [&](const float* xr, int qi, f32x4 (&xq)[8]) {
        #pragma unroll
        for (int s = 0; s < 4; ++s) {
            const int ks = qi * 4 + s;
            xq[2 * s]     = *(const f32x4*)(xr + ks * 32 + q * 8);
            xq[2 * s + 1] = *(const f32x4*)(xr + ks * 32 + q * 8 + 4);
        }
    };
    auto cvtQ = [&](const f32x4 (&xq)[8], f16x8* pf) {
        #pragma unroll
        for (int s = 0; s < 4; ++s) {
            f16x8 af;
            const float* a0 = (const float*)&xq[2 * s];
            #pragma unroll
            for (int j = 0; j < 8; ++j) af[j] = (_Float16)a0[j];
            pf[s] = af;
        }
    };
    auto mmaH = [&](int half, const f16x8* pf, f32x4& a0, f32x4& a1) {
        #pragma unroll
        for (int ksl = 0; ksl < 8; ++ksl) {
            const int oct = (half * 8 + ksl) * 4 + q;
            {
                const int po = oct ^ (ml & 7);
                const f16x8 bf = *(const f16x8*)&Wm[ml * KDIM + po * 8];
                a0 = __builtin_amdgcn_mfma_f32_16x16x32_f16(pf[ksl], bf, a0, 0, 0, 0);
            }
            {
                const int cB = 16 + ml;
                const int po = oct ^ (cB & 7);
                const f16x8 bf = *(const f16x8*)&Wm[cB * KDIM + po * 8];
                a1 = __builtin_amdgcn_mfma_f32_16x16x32_f16(pf[ksl], bf, a1, 0, 0, 0);
            }
        }
    };

    for (int g0 = sub * 16; g0 < cnt; g0 += 64) {
        const int idx = g0 + ml;
        const int row = rlm[(idx < cnt) ? idx : (cnt - 1)];
        const float* xr = x + (size_t)row * KDIM;

        f16x8 pafA[8], pafB[8];
        f32x4 acc0 = {}, acc1 = {};

        issueQ(xr, 0, xqA);
        issueQ(xr, 1, xqB);
        cvtQ(xqA, pafA);     issueQ(xr, 2, xqA);
        cvtQ(xqB, pafA + 4); issueQ(xr, 3, xqB);
        mmaH(0, pafA, acc0, acc1);          // covers quarters 2,3 in flight
        cvtQ(xqA, pafB);
        cvtQ(xqB, pafB + 4);
        mmaH(1, pafB, acc0, acc1);

        #pragma unroll
        for (int rg = 0; rg < 4; ++rg) {
            const int pos = g0 + q * 4 + rg;
            if (pos < cnt) {
                float* op = out + (size_t)rlm[pos] * NDIM + c0 + ml;
                op[0]  = acc0[rg];
                op[16] = acc1[rg];
            }
        }
    }
}

extern "C" void kernel_launch(void* const* d_in, const int* in_sizes, int n_in,
                              void* d_out, int out_size, void* d_ws, size_t ws_size,
                              hipStream_t stream) {
    const float* x    = (const float*)d_in[0];
    const int*   tids = (const int*)d_in[1];
    const float* W    = (const float*)d_in[2];
    float*       out  = (float*)d_out;
    const int n_rows  = in_sizes[1];   // 2048

    k_big<<<dim3(256), dim3(1024), 0, stream>>>(x, tids, W, out, n_rows);
}

// Round 8
// 104.809 us; speedup vs baseline: 1.2045x; 1.2045x over previous
//
#include <hip/hip_runtime.h>

// LearnedTaskSpecificLinear: out[n,o] = sum_i x[n,i] * W[task_ids[n], i, o]
// x: [2048,512] f32, task_ids: [2048] i32, W: [64,512,512] f32, out: [2048,512] f32
//
// Round 12: 64-col x 256-k units -> 256 B W-read granules (granule theory).
//   Warm-iteration counters (R11) show FETCH~0: kernel is Infinity-Cache-fed
//   yet stuck at ~2.8 TB/s. All schedule variants (R7-R11) pinned at 23-25us
//   -> the invariant is the 128B-granule / 2KB-stride W read of 32-col panels.
//   This round doubles the granule: unit = task x 64-col chunk (8 chunks/task,
//   512 blocks x 256 thr, 1 unit each). Each 16-lane group now reads 256 B
//   contiguous W per k-row.
//   LDS: Wt[2][64x256] f16 (64 KB) + lists -> 2 blocks/CU (R8's best
//   occupancy). launch_bounds(256,2): VGPR cap 256, audited peak ~180 (wrA 32
//   + wrB 32 + pafA 32 + pafB 32 + xa 32 transient + acc 16 + addr) - no spill.
//   Schedule = R8/R9's proven 2-buffer form: issue h0{s0->A,s1->B} -> scan ->
//   x-h0 gather (covers latency) -> stage A, issue h1s0->A -> stage B, issue
//   h1s1->B -> [lgkmcnt(0); s_barrier] -> mma(h0) + x-h1 gather -> stage h1
//   -> [lgkmcnt(0); s_barrier] -> mma(h1) + store. No vmcnt drain at barriers.
//   Swizzle po = oct ^ (c&7) and all fragment/store mappings unchanged
//   (read-side pattern identical to verified 32-col version: cB = ct*16+ml,
//   KH = 256).

#define NDIM 512
#define KDIM 512
#define NCOL 64
#define KH   256
#define GRID 512

typedef _Float16 f16x8 __attribute__((ext_vector_type(8)));
typedef float    f32x4 __attribute__((ext_vector_type(4)));
typedef int      i32x4 __attribute__((ext_vector_type(4)));

__global__ __launch_bounds__(256, 2) void k_g64(
    const float* __restrict__ x,
    const int*   __restrict__ tids,
    const float* __restrict__ W,
    float*       __restrict__ out,
    int n_rows)
{
    const int tid  = threadIdx.x;
    const int lane = tid & 63;
    const int wv   = tid >> 6;
    const int ml   = lane & 15;
    const int q    = lane >> 4;
    const int cg   = tid & 15;          // col group 0..15 (4 cols each -> 64 cols)
    const int sc4  = cg * 4;
    const int ot   = tid >> 4;          // base k-octet 0..15; stripes ot, ot+16

    // decode: task's 8 chunks all share bid&7 -> one XCD (x rows L2-resident)
    const int bid   = blockIdx.x;
    const int task  = (bid & 7) | ((bid >> 6) << 3);
    const int c0    = ((bid >> 3) & 7) * NCOL;

    __shared__ __align__(16) _Float16 Wt[2][NCOL * KH];   // 2 x 32 KB, swizzled
    __shared__ unsigned short rlw[4 * 128];               // per-wave private lists

    const float* Wg = W + (size_t)task * KDIM * NDIM + c0;

    // ---- tids: 8 consecutive rows per lane (this wave's 512-row quarter)
    const int rbase = wv * 512 + lane * 8;
    int tval[8];
    if (rbase + 7 < n_rows) {
        const i32x4 a = *(const i32x4*)(tids + rbase);
        const i32x4 b = *(const i32x4*)(tids + rbase + 4);
        tval[0] = a[0]; tval[1] = a[1]; tval[2] = a[2]; tval[3] = a[3];
        tval[4] = b[0]; tval[5] = b[1]; tval[6] = b[2]; tval[7] = b[3];
    } else {
        #pragma unroll
        for (int j = 0; j < 8; ++j)
            tval[j] = (rbase + j < n_rows) ? tids[rbase + j] : -1;
    }

    float4 wrA[8], wrB[8];

    // stripe (h, s): k-octet oct = ot + 16*s of K-half h; 8 rows x 16 B/thread.
    // Coalescing: 16 lanes (cg 0..15) cover 64 cols = 256 B contiguous per row.
    auto issueS = [&](int h, int s, float4 (&wb)[8]) {
        const size_t kb = (size_t)(h * KH) + (size_t)(ot + 16 * s) * 8;
        #pragma unroll
        for (int j = 0; j < 8; ++j)
            wb[j] = *(const float4*)(Wg + (kb + j) * NDIM + sc4);
    };
    auto stageS = [&](int h, int s, const float4 (&wb)[8]) {
        const int oct = ot + 16 * s;
        #pragma unroll
        for (int j2 = 0; j2 < 4; ++j2) {
            f16x8 h8;
            #pragma unroll
            for (int j = 0; j < 8; ++j)
                h8[j] = (_Float16)(((const float*)&wb[j])[j2]);
            const int c  = sc4 + j2;
            const int po = oct ^ (c & 7);
            *(f16x8*)&Wt[h][c * KH + po * 8] = h8;
        }
    };

    // ---- issue both stripes of K-half 0 up front
    issueS(0, 0, wrA);
    issueS(0, 1, wrB);

    // ---- ballot scan -> per-wave private row list (covers W h0 latency)
    int cloc = 0;
    #pragma unroll
    for (int j = 0; j < 8; ++j) {
        const bool m = (tval[j] == task);
        const unsigned long long bal = __ballot(m);
        const int rank = __popcll(bal & ((1ull << lane) - 1ull));
        const int slot = cloc + rank;
        if (m && slot < 128) rlw[wv * 128 + slot] = (unsigned short)(rbase + j);
        cloc += __popcll(bal);
    }
    if (cloc > 128) cloc = 128;

    auto load_half = [&](const float* xrp, int t, f16x8* paf) {
        #pragma unroll
        for (int h = 0; h < 2; ++h) {
            f32x4 xa[8];
            #pragma unroll
            for (int k2 = 0; k2 < 4; ++k2) {
                const int ks = h * 4 + k2;
                xa[2 * k2]     = *(const f32x4*)(xrp + t * KH + ks * 32 + q * 8);
                xa[2 * k2 + 1] = *(const f32x4*)(xrp + t * KH + ks * 32 + q * 8 + 4);
            }
            #pragma unroll
            for (int k2 = 0; k2 < 4; ++k2) {
                f16x8 af;
                const float* a0 = (const float*)&xa[2 * k2];
                #pragma unroll
                for (int j = 0; j < 8; ++j) af[j] = (_Float16)a0[j];
                paf[h * 4 + k2] = af;
            }
        }
    };

    auto mma_half = [&](int t, const f16x8* paf, f32x4* acc) {
        #pragma unroll
        for (int ks = 0; ks < 8; ++ks) {
            #pragma unroll
            for (int ct = 0; ct < 4; ++ct) {
                const int cB = ct * 16 + ml;
                const int po = (ks * 4 + q) ^ (cB & 7);
                const f16x8 bf = *(const f16x8*)&Wt[t][cB * KH + po * 8];
                acc[ct] = __builtin_amdgcn_mfma_f32_16x16x32_f16(paf[ks], bf, acc[ct], 0, 0, 0);
            }
        }
    };

    auto store_rows = [&](int g0, const f32x4* acc) {
        #pragma unroll
        for (int rg = 0; rg < 4; ++rg) {
            const int pos = g0 + q * 4 + rg;
            if (pos < cloc) {
                float* op = out + (size_t)rlw[wv * 128 + pos] * NDIM + c0 + ml;
                op[0]  = acc[0][rg];
                op[16] = acc[1][rg];
                op[32] = acc[2][rg];
                op[48] = acc[3][rg];
            }
        }
    };

    // ---- x half-0 gather (clamped dup addresses -> coalesced, no extra traffic)
    const float* xr = x;
    f16x8 pafA[8], pafB[8];
    if (cloc > 0) {
        const int idx = (ml < cloc) ? ml : (cloc - 1);
        xr = x + (size_t)rlw[wv * 128 + idx] * KDIM;
        load_half(xr, 0, pafA);
    }

    // ---- stage h0 stripes; refill buffers with h1 stripes (2-buffer stream)
    stageS(0, 0, wrA);
    issueS(1, 0, wrA);
    stageS(0, 1, wrB);
    issueS(1, 1, wrB);

    asm volatile("s_waitcnt lgkmcnt(0)" ::: "memory");
    __builtin_amdgcn_s_barrier();
    __builtin_amdgcn_sched_barrier(0);

    // ---- half-0 MFMA (hides h1 stripe latency), x half-1 gather
    f32x4 acc[4] = {};
    if (cloc > 0) mma_half(0, pafA, acc);
    if (cloc > 0) load_half(xr, 1, pafB);

    stageS(1, 0, wrA);
    stageS(1, 1, wrB);

    asm volatile("s_waitcnt lgkmcnt(0)" ::: "memory");
    __builtin_amdgcn_s_barrier();
    __builtin_amdgcn_sched_barrier(0);

    // ---- half-1 MFMA + store
    if (cloc > 0) {
        mma_half(1, pafB, acc);
        store_rows(0, acc);
    }

    // ---- rare: wave quarter with >16 matching rows; both Wt halves resident
    for (int g0 = 16; g0 < cloc; g0 += 16) {
        const int idx = g0 + ml;
        const float* xr2 = x + (size_t)rlw[wv * 128 + ((idx < cloc) ? idx : (cloc - 1))] * KDIM;
        f16x8 pf[8];
        f32x4 a2[4] = {};
        load_half(xr2, 0, pf);
        mma_half(0, pf, a2);
        load_half(xr2, 1, pf);
        mma_half(1, pf, a2);
        store_rows(g0, a2);
    }
}

extern "C" void kernel_launch(void* const* d_in, const int* in_sizes, int n_in,
                              void* d_out, int out_size, void* d_ws, size_t ws_size,
                              hipStream_t stream) {
    const float* x    = (const float*)d_in[0];
    const int*   tids = (const int*)d_in[1];
    const float* W    = (const float*)d_in[2];
    float*       out  = (float*)d_out;
    const int n_rows  = in_sizes[1];   // 2048

    k_g64<<<dim3(GRID), dim3(256), 0, stream>>>(x, tids, W, out, n_rows);
}